// Round 7
// baseline (126.306 us; speedup 1.0000x reference)
//
#include <hip/hip_runtime.h>
#include <math.h>

#define TB   512
#define HH   128      // input H=W
#define OHW  64       // output H=W
#define TR   32       // output rows per tile
#define NT   2        // tiles per plane (64/32)
#define XR   69       // input rows staged: 2*TR+5
#define XC   136      // 128 cols + pad (col offset +4, zeros in pad); row = 34 float4 slots
#define N0R  34       // n0 rows incl. 1-halo (out rows r0-1 .. r0+32)
#define N0C  68       // n0 row stride; interior col c at index c+2 (8B-aligned float2)
#define SLOTS_A (37 * 34)     // slab rows 0..36
#define SLOTS_T (XR * 34)     // all 2346 slots

typedef float f32x2 __attribute__((ext_vector_type(2)));

__device__ __forceinline__ float sigmoidf(float z) {
    return 1.0f / (1.0f + __expf(-z));
}

__global__ __launch_bounds__(TB, 6) void fused_densenet_kernel(
    const float* __restrict__ x,
    const float* __restrict__ maxgate,
    const float* __restrict__ mb,
    const float* __restrict__ pconvs,
    const float* __restrict__ pbs,
    const float* __restrict__ pgates,
    const float* __restrict__ gbs,
    float* __restrict__ out)
{
    __shared__ float xs[XR][XC];       // input slab, zero-padded (37.5 KB)
    __shared__ float n0s[N0R][N0C];    // n0, halo layout: col c -> index c+2 (9.0 KB)

    const int t     = threadIdx.x;
    const int bid   = blockIdx.x;
    const int tile  = bid & (NT - 1);
    const int plane = bid >> 1;        // b*256 + c
    const int c     = plane & 255;
    const int r0    = tile * TR;       // first global output row of tile

    // ---- uniform weights/biases (block-uniform address -> scalar-resident) ----
    // ws rows: 0=maxgate 1=p0 2=p1 3=p2 4=p3 5=gate0 6=gate2(leaf1+node)
    float ws[7][9];
#pragma unroll
    for (int i = 0; i < 9; ++i) {
        ws[0][i] = maxgate[c * 9  + i];
        ws[1][i] = pconvs [c * 36 + i * 4 + 0];
        ws[2][i] = pconvs [c * 36 + i * 4 + 1];
        ws[3][i] = pconvs [c * 36 + i * 4 + 2];
        ws[4][i] = pconvs [c * 36 + i * 4 + 3];
        ws[5][i] = pgates [c * 27 + i * 3 + 0];
        ws[6][i] = pgates [c * 27 + i * 3 + 2];
    }
    const float bmax = mb[c];
    const float bp0 = pbs[c * 4 + 0], bp1 = pbs[c * 4 + 1];
    const float bp2 = pbs[c * 4 + 2], bp3 = pbs[c * 4 + 3];
    const float bg0 = gbs[c * 3 + 0];   // leaf0 gate bias
    const float bg1 = gbs[c * 3 + 1];   // leaf1 gate bias
    const float bg2 = gbs[c * 3 + 2];   // node gate bias

    const float* xplane = x + (size_t)plane * (HH * HH);
    const int ir0 = 2 * r0 - 3;
    float4* xs4 = reinterpret_cast<float4*>(&xs[0][0]);   // slot s -> byte 16*s

    // ---- phase 0: stage half A (slab rows 0..36) + n0 side-col zeros ----
    for (int s = t; s < SLOTS_A; s += TB) {
        const int rr = s / 34;
        const int qq = s - rr * 34;
        float4 v = make_float4(0.f, 0.f, 0.f, 0.f);
        const int ir = ir0 + rr;
        if (qq >= 1 && qq <= 32 && (unsigned)ir < (unsigned)HH) {
            v = *reinterpret_cast<const float4*>(xplane + ir * HH + (qq - 1) * 4);
        }
        xs4[s] = v;
    }
    if (t < 2 * N0R) n0s[t >> 1][(t & 1) ? 66 : 1] = 0.f;   // side cols (outside image)
    __syncthreads();

    // ---- phase 1: issue half-B loads, compute top halo + k=0 under them ----
    float4 pb[3];
    int    pbslot[3];
#pragma unroll
    for (int j = 0; j < 3; ++j) {
        const int s = SLOTS_A + t + j * TB;
        pbslot[j] = (s < SLOTS_T) ? s : -1;
        float4 v = make_float4(0.f, 0.f, 0.f, 0.f);
        if (s < SLOTS_T) {
            const int rr = s / 34;
            const int qq = s - rr * 34;
            const int ir = ir0 + rr;     // rr>=37 -> ir>=34; only high edge can be OOB
            if (qq >= 1 && qq <= 32 && ir < HH) {
                v = *reinterpret_cast<const float4*>(xplane + ir * HH + (qq - 1) * 4);
            }
        }
        pb[j] = v;
    }

    // top n0 halo row (gr = r0-1), uses xs rows 0..2 (half A)
    if (t < 66) {
        const int gc = t - 1;            // -1..64
        const int gr = r0 - 1;
        float n0v = 0.f;
        if ((unsigned)gr < (unsigned)OHW && (unsigned)gc < (unsigned)OHW) {
            float ag = 0.f, a0 = 0.f, a1 = 0.f;
#pragma unroll
            for (int dr = 0; dr < 3; ++dr)
#pragma unroll
                for (int dc = 0; dc < 3; ++dc) {
                    const float v = xs[dr][2 * gc + dc + 3];
                    const int i = dr * 3 + dc;
                    ag += v * ws[5][i];
                    a0 += v * ws[1][i];
                    a1 += v * ws[2][i];
                }
            const float sg = sigmoidf(ag + bg0);
            n0v = sg * (a0 + bp0) + (1.f - sg) * (a1 + bp1);
        }
        n0s[0][t + 1] = n0v;
    }

    const int p  = t & 31;            // col pair: out cols {2p, 2p+1}
    const int g0 = t >> 5;            // row group 0..15
    float out1[2][2], n1v[2][2];

    // ---- stage-1 interior body (rows lr, xs rows 2lr+2..2lr+4) ----
#define STAGE1_BODY(K, LR)                                                              \
    {                                                                                   \
        const int lr = (LR);                                                            \
        const int gr = r0 + lr;                                                         \
        float a[7][2];                                                                  \
        _Pragma("unroll")                                                               \
        for (int ci = 0; ci < 7; ++ci) { a[ci][0] = 0.f; a[ci][1] = 0.f; }              \
        float mp0 = -INFINITY, mp1 = -INFINITY;                                         \
        _Pragma("unroll")                                                               \
        for (int dr = 0; dr < 3; ++dr) {                                                \
            const int xr = 2 * lr + 2 + dr;                                             \
            const float  v0 = xs[xr][4 * p + 3];                                        \
            const float4 vv = *reinterpret_cast<const float4*>(&xs[xr][4 * p + 4]);     \
            const bool rowok = (gr > 0) | (dr > 0);                                     \
            const float h0 = fmaxf(fmaxf((p > 0) ? v0 : -INFINITY, vv.x), vv.y);        \
            const float h1 = fmaxf(fmaxf(vv.y, vv.z), vv.w);                            \
            mp0 = fmaxf(mp0, rowok ? h0 : -INFINITY);                                   \
            mp1 = fmaxf(mp1, rowok ? h1 : -INFINITY);                                   \
            _Pragma("unroll")                                                           \
            for (int ci = 0; ci < 7; ++ci) {                                            \
                a[ci][0] += v0   * ws[ci][3*dr] + vv.x * ws[ci][3*dr+1] + vv.y * ws[ci][3*dr+2]; \
                a[ci][1] += vv.y * ws[ci][3*dr] + vv.z * ws[ci][3*dr+1] + vv.w * ws[ci][3*dr+2]; \
            }                                                                           \
        }                                                                               \
        const float sg0a = sigmoidf(a[5][0] + bg0);                                     \
        const float sg0b = sigmoidf(a[5][1] + bg0);                                     \
        const float n0a = sg0a * (a[1][0] + bp0) + (1.f - sg0a) * (a[2][0] + bp1);      \
        const float n0b = sg0b * (a[1][1] + bp0) + (1.f - sg0b) * (a[2][1] + bp1);      \
        *reinterpret_cast<f32x2*>(&n0s[lr + 1][2 * p + 2]) = (f32x2){ n0a, n0b };       \
        const float sg1a = sigmoidf(a[6][0] + bg1);                                     \
        const float sg1b = sigmoidf(a[6][1] + bg1);                                     \
        n1v[K][0] = sg1a * (a[3][0] + bp2) + (1.f - sg1a) * (a[4][0] + bp3);            \
        n1v[K][1] = sg1b * (a[3][1] + bp2) + (1.f - sg1b) * (a[4][1] + bp3);            \
        out1[K][0] = mp0 * (a[0][0] + bmax);                                            \
        out1[K][1] = mp1 * (a[0][1] + bmax);                                            \
    }

    STAGE1_BODY(0, g0)                 // lr 0..15, xs rows 2..34 (half A only)

    // write half B to LDS (loads have been in flight during k=0)
#pragma unroll
    for (int j = 0; j < 3; ++j) {
        if (pbslot[j] >= 0) xs4[pbslot[j]] = pb[j];
    }
    __syncthreads();

    // ---- phase 2: k=1 interior + bottom halo ----
    STAGE1_BODY(1, g0 + 16)            // lr 16..31, xs rows 34..68

    if (t < 66) {                      // bottom n0 halo row (gr = r0+32), xs rows 66..68
        const int gc = t - 1;
        const int gr = r0 + TR;
        float n0v = 0.f;
        if ((unsigned)gr < (unsigned)OHW && (unsigned)gc < (unsigned)OHW) {
            float ag = 0.f, a0 = 0.f, a1 = 0.f;
#pragma unroll
            for (int dr = 0; dr < 3; ++dr)
#pragma unroll
                for (int dc = 0; dc < 3; ++dc) {
                    const float v = xs[66 + dr][2 * gc + dc + 3];
                    const int i = dr * 3 + dc;
                    ag += v * ws[5][i];
                    a0 += v * ws[1][i];
                    a1 += v * ws[2][i];
                }
            const float sg = sigmoidf(ag + bg0);
            n0v = sg * (a0 + bp0) + (1.f - sg) * (a1 + bp1);
        }
        n0s[N0R - 1][t + 1] = n0v;
    }
    __syncthreads();

    // ---- phase 3: node gate conv on n0 (stride 1, pad 1) + combine + store ----
    float* oplane = out + (size_t)plane * (OHW * OHW);
#pragma unroll
    for (int k = 0; k < 2; ++k) {
        const int lr = g0 + 16 * k;
        float ag0 = 0.f, ag1 = 0.f;
        float n0c0 = 0.f, n0c1 = 0.f;
#pragma unroll
        for (int dr = 0; dr < 3; ++dr) {
            const float  e0  = n0s[lr + dr][2 * p + 1];
            const f32x2  mid = *reinterpret_cast<const f32x2*>(&n0s[lr + dr][2 * p + 2]);
            const float  e3  = n0s[lr + dr][2 * p + 4];
            ag0 += e0     * ws[6][3 * dr] + mid.x * ws[6][3 * dr + 1] + mid.y * ws[6][3 * dr + 2];
            ag1 += mid.x  * ws[6][3 * dr] + mid.y * ws[6][3 * dr + 1] + e3    * ws[6][3 * dr + 2];
            if (dr == 1) { n0c0 = mid.x; n0c1 = mid.y; }
        }
        const float ga = sigmoidf(ag0 + bg2);          // node gate: bias gbs[:,2]
        const float gb = sigmoidf(ag1 + bg2);
        const float r0v = out1[k][0] + n0c0 * ga + n1v[k][0] * (1.f - ga);
        const float r1v = out1[k][1] + n0c1 * gb + n1v[k][1] * (1.f - gb);
        __builtin_nontemporal_store((f32x2){ r0v, r1v },
            reinterpret_cast<f32x2*>(&oplane[(r0 + lr) * OHW + 2 * p]));
    }
#undef STAGE1_BODY
}

extern "C" void kernel_launch(void* const* d_in, const int* in_sizes, int n_in,
                              void* d_out, int out_size, void* d_ws, size_t ws_size,
                              hipStream_t stream) {
    const float* x       = (const float*)d_in[0];
    const float* maxgate = (const float*)d_in[1];
    const float* mb      = (const float*)d_in[2];
    const float* pconvs  = (const float*)d_in[3];
    const float* pbs     = (const float*)d_in[4];
    const float* pgates  = (const float*)d_in[5];
    const float* gbs     = (const float*)d_in[6];
    float* out           = (float*)d_out;

    const int blocks = 16 * 256 * NT;   // B * C * tiles-per-plane
    fused_densenet_kernel<<<blocks, TB, 0, stream>>>(
        x, maxgate, mb, pconvs, pbs, pgates, gbs, out);
}

// Round 8
// 113.721 us; speedup vs baseline: 1.1107x; 1.1107x over previous
//
#include <hip/hip_runtime.h>
#include <math.h>

#define HH  128      // input H=W
#define OHW 64       // output H=W
#define SR  16       // output rows per strip (4 strips/plane)

typedef float f32x2 __attribute__((ext_vector_type(2)));

__device__ __forceinline__ float sigmoidf(float z) {
    return 1.0f / (1.0f + __expf(-z));
}

// Block = 128 threads = 2 waves; each wave = 2 lane-groups of 32; each group
// owns a 16-row strip of one 64x64 output plane. Thread (p = lane&31) owns
// output cols {2p, 2p+1} and rolls down the strip row by row. No LDS, no
// barriers: input window (3 rows x 5 cols) and n0 (3 rows x 2 cols + shuffled
// halos) live in registers; stage-2 output trails stage-1 by one row.
__global__ __launch_bounds__(128, 6) void fused_densenet_kernel(
    const float* __restrict__ x,
    const float* __restrict__ maxgate,
    const float* __restrict__ mb,
    const float* __restrict__ pconvs,
    const float* __restrict__ pbs,
    const float* __restrict__ pgates,
    const float* __restrict__ gbs,
    float* __restrict__ out)
{
    const int t     = threadIdx.x;
    const int lane  = t & 63;
    const int wv    = t >> 6;          // wave 0..1
    const int p     = lane & 31;       // col-pair index
    const int g     = lane >> 5;       // group in wave
    const int plane = blockIdx.x;      // 4096 planes, 1 plane/block (c block-uniform)
    const int c     = plane & 255;
    const int rs    = ((wv << 1) | g) * SR;   // strip start row

    // ---- weights/biases: c is block-uniform -> scalar loads / SGPR-resident ----
    // ws rows: 0=maxgate 1=p0 2=p1 3=p2 4=p3 5=gate0 6=gate2(leaf1+node)
    float ws[7][9];
#pragma unroll
    for (int i = 0; i < 9; ++i) {
        ws[0][i] = maxgate[c * 9  + i];
        ws[1][i] = pconvs [c * 36 + i * 4 + 0];
        ws[2][i] = pconvs [c * 36 + i * 4 + 1];
        ws[3][i] = pconvs [c * 36 + i * 4 + 2];
        ws[4][i] = pconvs [c * 36 + i * 4 + 3];
        ws[5][i] = pgates [c * 27 + i * 3 + 0];
        ws[6][i] = pgates [c * 27 + i * 3 + 2];
    }
    const float bmax = mb[c];
    const float bp0 = pbs[c * 4 + 0], bp1 = pbs[c * 4 + 1];
    const float bp2 = pbs[c * 4 + 2], bp3 = pbs[c * 4 + 3];
    const float bg0 = gbs[c * 3 + 0];   // leaf0 gate bias
    const float bg1 = gbs[c * 3 + 1];   // leaf1 gate bias
    const float bg2 = gbs[c * 3 + 2];   // node gate bias

    const float* xbase = x + (size_t)plane * (HH * HH) + 4 * p;
    float*       op    = out + (size_t)plane * (OHW * OHW);
    const float4 zero4 = make_float4(0.f, 0.f, 0.f, 0.f);

// load input row IR: float4 of cols 4p..4p+3 + left-halo col 4p-1 (0 at edge)
#define LOADROW(IR, V, L) {                                                     \
        V = zero4;                                                              \
        if ((IR) < HH) V = *reinterpret_cast<const float4*>(xbase + (IR) * HH); \
        const float _s = __shfl_up(V.w, 1);                                     \
        L = (p > 0) ? _s : 0.f; }

// stage 1 at one output row from window rows A,B,C (weights rows 0,1,2)
#define STAGE1(AV,AL,AOK, BV,BL, CV,CL, N0X,N0Y, O1X,O1Y, LNX,LNY) {            \
        float ac[7][2];                                                         \
        _Pragma("unroll")                                                       \
        for (int ci = 0; ci < 7; ++ci) {                                        \
            ac[ci][0] = AL   * ws[ci][0] + AV.x * ws[ci][1] + AV.y * ws[ci][2]; \
            ac[ci][1] = AV.y * ws[ci][0] + AV.z * ws[ci][1] + AV.w * ws[ci][2]; \
            ac[ci][0]+= BL   * ws[ci][3] + BV.x * ws[ci][4] + BV.y * ws[ci][5]; \
            ac[ci][1]+= BV.y * ws[ci][3] + BV.z * ws[ci][4] + BV.w * ws[ci][5]; \
            ac[ci][0]+= CL   * ws[ci][6] + CV.x * ws[ci][7] + CV.y * ws[ci][8]; \
            ac[ci][1]+= CV.y * ws[ci][6] + CV.z * ws[ci][7] + CV.w * ws[ci][8]; \
        }                                                                       \
        const float hA0 = fmaxf(fmaxf((p > 0) ? AL : -INFINITY, AV.x), AV.y);   \
        const float hA1 = fmaxf(fmaxf(AV.y, AV.z), AV.w);                       \
        const float hB0 = fmaxf(fmaxf((p > 0) ? BL : -INFINITY, BV.x), BV.y);   \
        const float hB1 = fmaxf(fmaxf(BV.y, BV.z), BV.w);                       \
        const float hC0 = fmaxf(fmaxf((p > 0) ? CL : -INFINITY, CV.x), CV.y);   \
        const float hC1 = fmaxf(fmaxf(CV.y, CV.z), CV.w);                       \
        const float mp0 = fmaxf(fmaxf((AOK) ? hA0 : -INFINITY, hB0), hC0);      \
        const float mp1 = fmaxf(fmaxf((AOK) ? hA1 : -INFINITY, hB1), hC1);      \
        const float sg0a = sigmoidf(ac[5][0] + bg0);                            \
        const float sg0b = sigmoidf(ac[5][1] + bg0);                            \
        N0X = sg0a * (ac[1][0] + bp0) + (1.f - sg0a) * (ac[2][0] + bp1);        \
        N0Y = sg0b * (ac[1][1] + bp0) + (1.f - sg0b) * (ac[2][1] + bp1);        \
        const float sg1a = sigmoidf(ac[6][0] + bg1);                            \
        const float sg1b = sigmoidf(ac[6][1] + bg1);                            \
        LNX = sg1a * (ac[3][0] + bp2) + (1.f - sg1a) * (ac[4][0] + bp3);        \
        LNY = sg1b * (ac[3][1] + bp2) + (1.f - sg1b) * (ac[4][1] + bp3);        \
        O1X = mp0 * (ac[0][0] + bmax);                                          \
        O1Y = mp1 * (ac[0][1] + bmax); }

// horizontal n0 halos via lane shuffles (0 outside image)
#define N0LR(NX, NY, NL, NR) {                  \
        const float _u = __shfl_up(NY, 1);      \
        NL = (p > 0)  ? _u : 0.f;               \
        const float _d = __shfl_down(NX, 1);    \
        NR = (p < 31) ? _d : 0.f; }

// stage-2 emit of output row ROW using n0 state {n2*, n1*, cc*} + pending out1/n1
#define EMIT(ROW, POX,POY, PNX,PNY) {                                           \
        const float ag0 = n2l * ws[6][0] + n2x * ws[6][1] + n2y * ws[6][2]      \
                        + n1l * ws[6][3] + n1x * ws[6][4] + n1y * ws[6][5]      \
                        + ccl * ws[6][6] + ccx * ws[6][7] + ccy * ws[6][8];     \
        const float ag1 = n2x * ws[6][0] + n2y * ws[6][1] + n2r * ws[6][2]      \
                        + n1x * ws[6][3] + n1y * ws[6][4] + n1r * ws[6][5]      \
                        + ccx * ws[6][6] + ccy * ws[6][7] + ccr * ws[6][8];     \
        const float ga = sigmoidf(ag0 + bg2);                                   \
        const float gb = sigmoidf(ag1 + bg2);                                   \
        f32x2 rv;                                                               \
        rv.x = POX + n1x * ga + PNX * (1.f - ga);                               \
        rv.y = POY + n1y * gb + PNY * (1.f - gb);                               \
        __builtin_nontemporal_store(rv,                                         \
            reinterpret_cast<f32x2*>(op + (ROW) * OHW + 2 * p)); }

    float4 Av, Bv, Cv; float Al, Bl, Cl; bool Aok;
    float n2x = 0.f, n2y = 0.f, n2l = 0.f, n2r = 0.f;   // n0[r-2]
    float n1x = 0.f, n1y = 0.f, n1l = 0.f, n1r = 0.f;   // n0[r-1]
    float ccx, ccy, ccl, ccr;                           // n0[r]

    // ---- prologue: n0[rs-1] (boundary row of neighbor strip; 0 above image) ----
    if (rs > 0) {
        float4 Pv, Qv, Rv; float Pl, Ql, Rl;
        LOADROW(2 * rs - 3, Pv, Pl);
        LOADROW(2 * rs - 2, Qv, Ql);
        LOADROW(2 * rs - 1, Rv, Rl);
        float d0, d1, d2, d3;
        STAGE1(Pv, Pl, true, Qv, Ql, Rv, Rl, n1x, n1y, d0, d1, d2, d3);
        N0LR(n1x, n1y, n1l, n1r);
        Av = Rv; Al = Rl; Aok = true;
    } else {
        Av = zero4; Al = 0.f; Aok = false;   // input row -1
    }
    LOADROW(2 * rs,     Bv, Bl);
    LOADROW(2 * rs + 1, Cv, Cl);

    float pox, poy, pnx, pny;    // pending out1 / leaf-n1 for row r-1

    // ---- iteration 0 (rr = rs): stage-1 only ----
    STAGE1(Av, Al, Aok, Bv, Bl, Cv, Cl, ccx, ccy, pox, poy, pnx, pny);
    N0LR(ccx, ccy, ccl, ccr);
    n2x = n1x; n2y = n1y; n2l = n1l; n2r = n1r;
    n1x = ccx; n1y = ccy; n1l = ccl; n1r = ccr;
    Av = Cv; Al = Cl; Aok = true;
    LOADROW(2 * rs + 2, Bv, Bl);
    LOADROW(2 * rs + 3, Cv, Cl);

    // ---- main loop: stage-1 row rr, emit row rr-1 ----
#pragma unroll 4
    for (int i = 1; i < SR; ++i) {
        const int rr = rs + i;
        float nox, noy, nnx, nny;
        STAGE1(Av, Al, true, Bv, Bl, Cv, Cl, ccx, ccy, nox, noy, nnx, nny);
        N0LR(ccx, ccy, ccl, ccr);
        EMIT(rr - 1, pox, poy, pnx, pny);
        n2x = n1x; n2y = n1y; n2l = n1l; n2r = n1r;
        n1x = ccx; n1y = ccy; n1l = ccl; n1r = ccr;
        pox = nox; poy = noy; pnx = nnx; pny = nny;
        Av = Cv; Al = Cl;
        LOADROW(2 * rr + 2, Bv, Bl);    // guarded: rows >127 load as zeros
        LOADROW(2 * rr + 3, Cv, Cl);
    }

    // ---- epilogue (rr = rs+16): n0 boundary row (0 below image), emit last row ----
    {
        const int rr = rs + SR;
        ccx = 0.f; ccy = 0.f;
        if (rr < OHW) {
            float d0, d1, d2, d3;
            STAGE1(Av, Al, true, Bv, Bl, Cv, Cl, ccx, ccy, d0, d1, d2, d3);
        }
        N0LR(ccx, ccy, ccl, ccr);
        EMIT(rr - 1, pox, poy, pnx, pny);
    }
#undef LOADROW
#undef STAGE1
#undef N0LR
#undef EMIT
}

extern "C" void kernel_launch(void* const* d_in, const int* in_sizes, int n_in,
                              void* d_out, int out_size, void* d_ws, size_t ws_size,
                              hipStream_t stream) {
    const float* x       = (const float*)d_in[0];
    const float* maxgate = (const float*)d_in[1];
    const float* mb      = (const float*)d_in[2];
    const float* pconvs  = (const float*)d_in[3];
    const float* pbs     = (const float*)d_in[4];
    const float* pgates  = (const float*)d_in[5];
    const float* gbs     = (const float*)d_in[6];
    float* out           = (float*)d_out;

    const int blocks = 16 * 256;   // one plane per block
    fused_densenet_kernel<<<blocks, 128, 0, stream>>>(
        x, maxgate, mb, pconvs, pbs, pgates, gbs, out);
}

// Round 9
// 100.929 us; speedup vs baseline: 1.2514x; 1.1267x over previous
//
#include <hip/hip_runtime.h>
#include <math.h>

#define TB   512
#define HH   128     // input H=W
#define OHW  64      // output H=W
#define TR   16      // output rows per tile
#define NT   4       // tiles per plane
#define XR   37      // slab rows per tile: 2*TR+5
#define N0C  68      // n0 row stride; out col c at index c+2

typedef float f32x2 __attribute__((ext_vector_type(2)));

__device__ __forceinline__ float sigmoidf(float z) {
    return 1.0f / (1.0f + __expf(-z));
}

__device__ __forceinline__ void gl2lds16(const float* g, float* l) {
    __builtin_amdgcn_global_load_lds(
        (const __attribute__((address_space(1))) void*)g,
        (__attribute__((address_space(3))) void*)l, 16, 0, 0);
}
__device__ __forceinline__ void gl2lds4(const float* g, float* l) {
    __builtin_amdgcn_global_load_lds(
        (const __attribute__((address_space(1))) void*)g,
        (__attribute__((address_space(3))) void*)l, 4, 0, 0);
}

// Stage tile tt's slab (input rows 2*tt*TR-3 .. +XR-1, zero-padded at image
// edges) into xsbuf[XR][HH] asynchronously. Slab is contiguous in global
// memory; LDS layout is linear -> global_load_lds applies directly.
__device__ __forceinline__ void stage_tile(float* xsbuf, const float* xplane,
                                           int tt, int t, int wv, int lane) {
    const int ir0  = 2 * tt * TR - 3;
    const int lo   = ir0 < 0 ? 0 : ir0;
    const int hie  = ir0 + XR - 1;
    const int hi   = hie > HH - 1 ? HH - 1 : hie;
    const int ztop = lo - ir0;            // 0 or 3 zero rows at top
    const int zbot = hie - hi;            // 0 or 2 zero rows at bottom
    if (ztop && t < ztop * HH) xsbuf[t] = 0.f;
    if (zbot && t < zbot * HH) xsbuf[(XR - zbot) * HH + t] = 0.f;
    const int    nfl  = (hi - lo + 1) * HH;       // valid floats (multiple of 128)
    const float* gsrc = xplane + lo * HH;
    float*       ldst = xsbuf + ztop * HH;
    const int nchunk = nfl >> 8;                  // 1KB chunks (64 lanes x 16B)
    for (int k = wv; k < nchunk; k += TB / 64) {
        gl2lds16(gsrc + (k << 8) + lane * 4, ldst + (k << 8));
    }
    if ((nfl & 255) && wv == 0) {                 // 512B tail: two width-4 issues
        const int off = nchunk << 8;
        gl2lds4(gsrc + off + lane,      ldst + off);
        gl2lds4(gsrc + off + 64 + lane, ldst + off + 64);
    }
}

__global__ __launch_bounds__(TB, 6) void fused_densenet_kernel(
    const float* __restrict__ x,
    const float* __restrict__ maxgate,
    const float* __restrict__ mb,
    const float* __restrict__ pconvs,
    const float* __restrict__ pbs,
    const float* __restrict__ pgates,
    const float* __restrict__ gbs,
    float* __restrict__ out)
{
    __shared__ float xs[2][XR][HH];      // double-buffered slab (37.9 KB)
    __shared__ float n0s[TR + 2][N0C];   // n0 with 1-halo (4.9 KB)

    const int t     = threadIdx.x;
    const int lane  = t & 63;
    const int wv    = t >> 6;            // wave 0..7
    const int plane = blockIdx.x;        // one plane per block (c block-uniform)
    const int c     = plane & 255;
    const int p     = t & 31;            // col pair: out cols {2p, 2p+1}
    const int lr    = t >> 5;            // local output row 0..15

    // ---- weights/biases (block-uniform address -> scalar-resident) ----
    // ws rows: 0=maxgate 1=p0 2=p1 3=p2 4=p3 5=gate0 6=gate2(leaf1+node)
    float ws[7][9];
#pragma unroll
    for (int i = 0; i < 9; ++i) {
        ws[0][i] = maxgate[c * 9  + i];
        ws[1][i] = pconvs [c * 36 + i * 4 + 0];
        ws[2][i] = pconvs [c * 36 + i * 4 + 1];
        ws[3][i] = pconvs [c * 36 + i * 4 + 2];
        ws[4][i] = pconvs [c * 36 + i * 4 + 3];
        ws[5][i] = pgates [c * 27 + i * 3 + 0];
        ws[6][i] = pgates [c * 27 + i * 3 + 2];
    }
    const float bmax = mb[c];
    const float bp0 = pbs[c * 4 + 0], bp1 = pbs[c * 4 + 1];
    const float bp2 = pbs[c * 4 + 2], bp3 = pbs[c * 4 + 3];
    const float bg0 = gbs[c * 3 + 0];   // leaf0 gate bias
    const float bg1 = gbs[c * 3 + 1];   // leaf1 gate bias
    const float bg2 = gbs[c * 3 + 2];   // node gate bias

    const float* xplane = x + (size_t)plane * (HH * HH);
    float*       op     = out + (size_t)plane * (OHW * OHW);

    // ---- prologue: stage tile 0; side cols of n0 are always 0 (image edge) ----
    stage_tile(&xs[0][0][0], xplane, 0, t, wv, lane);
    if (t < 2 * (TR + 2)) n0s[t >> 1][(t & 1) ? 66 : 1] = 0.f;
    __syncthreads();                      // drains vmcnt -> tile 0 ready

    for (int tt = 0; tt < NT; ++tt) {
        const int r0  = tt * TR;
        const int buf = tt & 1;

        // issue next tile's staging (stays in flight through this tile's compute)
        if (tt + 1 < NT) stage_tile(&xs[buf ^ 1][0][0], xplane, tt + 1, t, wv, lane);

        // ---- n0 halo rows (gr = r0-1 and r0+TR; zero outside image) ----
        if (t < 132) {
            const int hb = (t >= 66);            // 0 top, 1 bottom
            const int cc = hb ? t - 66 : t;      // 0..65
            const int gc = cc - 1;               // out col -1..64
            const int gr = hb ? r0 + TR : r0 - 1;
            float n0v = 0.f;
            if ((unsigned)gr < (unsigned)OHW && (unsigned)gc < (unsigned)OHW) {
                float ag = 0.f, a0 = 0.f, a1 = 0.f;
#pragma unroll
                for (int dr = 0; dr < 3; ++dr) {
                    const float* row = xs[buf][(hb ? 2 * TR + 2 : 0) + dr];
                    const float w0 = (gc > 0) ? row[2 * gc - 1] : 0.f;
                    const float w1 = row[2 * gc];
                    const float w2 = row[2 * gc + 1];
                    ag += w0 * ws[5][3*dr] + w1 * ws[5][3*dr+1] + w2 * ws[5][3*dr+2];
                    a0 += w0 * ws[1][3*dr] + w1 * ws[1][3*dr+1] + w2 * ws[1][3*dr+2];
                    a1 += w0 * ws[2][3*dr] + w1 * ws[2][3*dr+1] + w2 * ws[2][3*dr+2];
                }
                const float sg = sigmoidf(ag + bg0);
                n0v = sg * (a0 + bp0) + (1.f - sg) * (a1 + bp1);
            }
            n0s[hb ? TR + 1 : 0][cc + 1] = n0v;
        }

        // ---- stage-1 interior: 1 row x 2 cols per thread ----
        const int gr = r0 + lr;
        float a[7][2];
#pragma unroll
        for (int ci = 0; ci < 7; ++ci) { a[ci][0] = 0.f; a[ci][1] = 0.f; }
        float mp0 = -INFINITY, mp1 = -INFINITY;
#pragma unroll
        for (int dr = 0; dr < 3; ++dr) {
            const float* row = xs[buf][2 * lr + 2 + dr];
            const float  v0 = (p > 0) ? row[4 * p - 1] : 0.f;
            const float4 vv = *reinterpret_cast<const float4*>(&row[4 * p]);
            const bool rowok = (gr > 0) | (dr > 0);
            const float h0 = fmaxf(fmaxf((p > 0) ? v0 : -INFINITY, vv.x), vv.y);
            const float h1 = fmaxf(fmaxf(vv.y, vv.z), vv.w);
            mp0 = fmaxf(mp0, rowok ? h0 : -INFINITY);
            mp1 = fmaxf(mp1, rowok ? h1 : -INFINITY);
#pragma unroll
            for (int ci = 0; ci < 7; ++ci) {
                a[ci][0] += v0   * ws[ci][3*dr] + vv.x * ws[ci][3*dr+1] + vv.y * ws[ci][3*dr+2];
                a[ci][1] += vv.y * ws[ci][3*dr] + vv.z * ws[ci][3*dr+1] + vv.w * ws[ci][3*dr+2];
            }
        }
        const float sg0a = sigmoidf(a[5][0] + bg0);
        const float sg0b = sigmoidf(a[5][1] + bg0);
        const float n0a = sg0a * (a[1][0] + bp0) + (1.f - sg0a) * (a[2][0] + bp1);
        const float n0b = sg0b * (a[1][1] + bp0) + (1.f - sg0b) * (a[2][1] + bp1);
        *reinterpret_cast<f32x2*>(&n0s[lr + 1][2 * p + 2]) = (f32x2){ n0a, n0b };
        const float sg1a = sigmoidf(a[6][0] + bg1);    // leaf1 gate: bias gbs[:,1]
        const float sg1b = sigmoidf(a[6][1] + bg1);
        const float n1a  = sg1a * (a[3][0] + bp2) + (1.f - sg1a) * (a[4][0] + bp3);
        const float n1b  = sg1b * (a[3][1] + bp2) + (1.f - sg1b) * (a[4][1] + bp3);
        const float o1a  = mp0 * (a[0][0] + bmax);
        const float o1b  = mp1 * (a[0][1] + bmax);

        // LDS-only barrier: n0 visible to all waves; prefetch vmcnt stays in flight
        asm volatile("s_waitcnt lgkmcnt(0)\n\ts_barrier" ::: "memory");

        // ---- stage 2: node gate conv on n0 (stride 1, pad 1) + combine + store ----
        float ag0 = 0.f, ag1 = 0.f, n0c0 = 0.f, n0c1 = 0.f;
#pragma unroll
        for (int dr = 0; dr < 3; ++dr) {
            const float e0  = n0s[lr + dr][2 * p + 1];
            const f32x2 mid = *reinterpret_cast<const f32x2*>(&n0s[lr + dr][2 * p + 2]);
            const float e3  = n0s[lr + dr][2 * p + 4];
            ag0 += e0    * ws[6][3*dr] + mid.x * ws[6][3*dr+1] + mid.y * ws[6][3*dr+2];
            ag1 += mid.x * ws[6][3*dr] + mid.y * ws[6][3*dr+1] + e3    * ws[6][3*dr+2];
            if (dr == 1) { n0c0 = mid.x; n0c1 = mid.y; }
        }
        const float ga = sigmoidf(ag0 + bg2);          // node gate: bias gbs[:,2]
        const float gb = sigmoidf(ag1 + bg2);
        f32x2 rv;
        rv.x = o1a + n0c0 * ga + n1a * (1.f - ga);
        rv.y = o1b + n0c1 * gb + n1b * (1.f - gb);
        __builtin_nontemporal_store(rv,
            reinterpret_cast<f32x2*>(op + gr * OHW + 2 * p));

        // full barrier: drains next-tile prefetch; guards n0s + xs buffer reuse
        __syncthreads();
    }
}

extern "C" void kernel_launch(void* const* d_in, const int* in_sizes, int n_in,
                              void* d_out, int out_size, void* d_ws, size_t ws_size,
                              hipStream_t stream) {
    const float* x       = (const float*)d_in[0];
    const float* maxgate = (const float*)d_in[1];
    const float* mb      = (const float*)d_in[2];
    const float* pconvs  = (const float*)d_in[3];
    const float* pbs     = (const float*)d_in[4];
    const float* pgates  = (const float*)d_in[5];
    const float* gbs     = (const float*)d_in[6];
    float* out           = (float*)d_out;

    const int blocks = 16 * 256;   // one plane per block
    fused_densenet_kernel<<<blocks, TB, 0, stream>>>(
        x, maxgate, mb, pconvs, pbs, pgates, gbs, out);
}